// Round 9
// baseline (137.063 us; speedup 1.0000x reference)
//
#include <hip/hip_runtime.h>
#include <hip/hip_bf16.h>

typedef unsigned short ushort_t;
typedef __attribute__((ext_vector_type(8))) short short8;   // 8 bf16 (4 VGPRs)
typedef __attribute__((ext_vector_type(4))) short short4v;  // 4 bf16 (2 VGPRs)
typedef __attribute__((ext_vector_type(4))) float f32x4;    // 4 fp32 acc

__device__ __forceinline__ float bf2f(ushort_t u) {
    unsigned int x = ((unsigned int)u) << 16;
    float f; __builtin_memcpy(&f, &x, 4); return f;
}
__device__ __forceinline__ ushort_t f2bf(float f) {
    __hip_bfloat16 h = __float2bfloat16(f);
    ushort_t u; __builtin_memcpy(&u, &h, 2); return u;
}
__device__ __forceinline__ unsigned packbf2(float a, float b) {
    return (unsigned)f2bf(a) | ((unsigned)f2bf(b) << 16);
}

// Direct-to-LDS DMA, 16B per lane. No dest VGPR -> the compiler cannot sink it.
__device__ __forceinline__ void gload16(const void* g, void* l) {
    __builtin_amdgcn_global_load_lds(
        (const __attribute__((address_space(1))) unsigned int*)g,
        (__attribute__((address_space(3))) unsigned int*)l, 16, 0, 0);
}

constexpr int E  = 1024;
constexpr int Hd = 64;
constexpr int S  = 2048;
constexpr int ROWS = 8 * 2048;   // 16384
constexpr int NTOT = 192;
constexpr int LSTA = 88;         // attn LDS row stride (R1-measured layout)
constexpr int BM   = 32;         // proj rows per block (grid 512 = 2 blocks/CU)

// ---------------------------------------------------------------------------
// prep: WT[192][1024] bf16, rows 0-63 = Wq^T, 64-127 = Wk^T, 128-191 = Wv^T
__global__ __launch_bounds__(256)
void prep_wt(const float* __restrict__ Wk, const float* __restrict__ Wq,
             const float* __restrict__ Wv, ushort_t* __restrict__ WT)
{
    int idx = blockIdx.x * 256 + threadIdx.x;
    int n = idx >> 10;
    int kk = idx & 1023;
    const float* W = (n < 64) ? Wq : ((n < 128) ? Wk : Wv);
    int h = n & 63;
    WT[idx] = f2bf(W[kk * Hd + h]);
}

// ---------------------------------------------------------------------------
// Projection v14: weight LDS staging ELIMINATED (it was 60% of the per-body
// DMA bytes). Weights read direct from L2-resident WT (v7's exact per-lane
// fragment pattern, each fragment read once per block by its owning wave)
// into PINNED ping-pong register sets: WLOAD(i+2) issued after barrier2,
// sched_barrier(0) prevents the sink that killed v7/v10's prefetch (VGPR=52
// proof in R4). x stays DMA-staged (XOR swizzle verified in v11/v13).
// BM=32, 256 thr, grid 512 -> TRUE 2 blocks/CU (v13's grid-256 mistake
// fixed); per-body sync stalls absorbed by the co-resident block (m114).
// Ledger: 8 VMEM/iter (2 x-DMA + 6 wloads); prologue 16 outstanding;
// steady vmcnt(8) drains exactly body i's {STAGE,WLOAD}; tail vmcnt(0).
__global__ __launch_bounds__(256, 2)
void proj_v14(const float* __restrict__ x, const ushort_t* __restrict__ WT,
              ushort_t* __restrict__ qo, ushort_t* __restrict__ ko,
              ushort_t* __restrict__ vTo)
{
    __shared__ alignas(16) float XS[2][BM * 64];   // 8KB x-tile x2

    const int t    = threadIdx.x;        // 0..255
    const int w    = t >> 6;             // 0..3 (col-group)
    const int lane = t & 63;
    const int m    = lane & 15;
    const int g    = lane >> 4;
    const int rl   = m & 7;              // swizzle key (row&7 == m&7 at reads)
    const int rb   = blockIdx.x * BM;

    f32x4 accq[2], acck[2], accv[2];
    #pragma unroll
    for (int j = 0; j < 2; ++j) {
        accq[j] = (f32x4){0.f, 0.f, 0.f, 0.f};
        acck[j] = (f32x4){0.f, 0.f, 0.f, 0.f};
        accv[j] = (f32x4){0.f, 0.f, 0.f, 0.f};
    }

    // ---- x staging sources (inverse-swizzled; 2 units of 16B per thread)
    const int r0 = t >> 4,         u0 = (t & 15) ^ (r0 & 7);
    const int r1 = (t + 256) >> 4, u1 = (t & 15) ^ (r1 & 7);
    const float* xsrc0 = x + (size_t)(rb + r0) * E + u0 * 4;
    const float* xsrc1 = x + (size_t)(rb + r1) * E + u1 * 4;

    // ---- weight fragment pointers (v7 pattern; per-lane, L2-resident)
    const ushort_t* wqp = WT + (size_t)(w * 16 + m) * E + g * 8;
    const ushort_t* wkp = wqp + (size_t)64 * E;
    const ushort_t* wvp = wqp + (size_t)128 * E;

    // ---- x fragment LDS offsets (lane constants; f32 index)
    int xiA[2][2], xiB[2][2];            // [h][kt]
    #pragma unroll
    for (int h = 0; h < 2; ++h)
        #pragma unroll
        for (int kt = 0; kt < 2; ++kt) {
            const int row = h * 16 + m;
            const int U   = kt * 8 + 2 * g;
            xiA[h][kt] = (row * 16 + (U ^ rl)) * 4;
            xiB[h][kt] = (row * 16 + ((U + 1) ^ rl)) * 4;
        }

    auto STAGE = [&](int buf, int c) {   // 2 gload16 / thread
        const int k0 = c * 64;
        char* xb = (char*)&XS[buf][0];
        gload16(xsrc0 + k0, xb + (size_t)t * 16);
        gload16(xsrc1 + k0, xb + (size_t)(t + 256) * 16);
    };

    auto WLOAD = [&](short8* wq, short8* wk, short8* wv, int c) {  // 6 loads
        const int k0 = c * 64;
        #pragma unroll
        for (int kt = 0; kt < 2; ++kt) {
            wq[kt] = *(const short8*)(wqp + k0 + kt * 32);
            wk[kt] = *(const short8*)(wkp + k0 + kt * 32);
            wv[kt] = *(const short8*)(wvp + k0 + kt * 32);
        }
    };

    auto COMPUTE = [&](int buf, const short8* wq, const short8* wk,
                       const short8* wv) {
        #pragma unroll
        for (int kt = 0; kt < 2; ++kt) {
            #pragma unroll
            for (int h = 0; h < 2; ++h) {
                float4 A = *(const float4*)&XS[buf][xiA[h][kt]];
                float4 B = *(const float4*)&XS[buf][xiB[h][kt]];
                short8 a;
                {
                    unsigned u4[4];
                    u4[0] = packbf2(A.x, A.y);
                    u4[1] = packbf2(A.z, A.w);
                    u4[2] = packbf2(B.x, B.y);
                    u4[3] = packbf2(B.z, B.w);
                    __builtin_memcpy(&a, u4, 16);
                }
                accq[h] = __builtin_amdgcn_mfma_f32_16x16x32_bf16(a, wq[kt], accq[h], 0, 0, 0);
                acck[h] = __builtin_amdgcn_mfma_f32_16x16x32_bf16(a, wk[kt], acck[h], 0, 0, 0);
                accv[h] = __builtin_amdgcn_mfma_f32_16x16x32_bf16(wv[kt], a, accv[h], 0, 0, 0);
            }
        }
    };

    short8 wqA[2], wkA[2], wvA[2], wqB[2], wkB[2], wvB[2];

    // ---- prologue: bodies 0,1 in flight (16 VMEM outstanding)
    STAGE(0, 0); WLOAD(wqA, wkA, wvA, 0);
    STAGE(1, 1); WLOAD(wqB, wkB, wvB, 1);

    // ---- main loop (fully unrolled; buf/set selection static)
    #pragma unroll
    for (int i = 0; i < 16; ++i) {
        if (i < 15) { asm volatile("s_waitcnt vmcnt(8)" ::: "memory"); }
        else        { asm volatile("s_waitcnt vmcnt(0)" ::: "memory"); }
        __builtin_amdgcn_sched_barrier(0);
        __builtin_amdgcn_s_barrier();
        if ((i & 1) == 0) COMPUTE(0, wqA, wkA, wvA);
        else              COMPUTE(1, wqB, wkB, wvB);
        __builtin_amdgcn_s_barrier();
        if (i + 2 < 16) {
            STAGE(i & 1, i + 2);
            if ((i & 1) == 0) WLOAD(wqA, wkA, wvA, i + 2);
            else              WLOAD(wqB, wkB, wvB, i + 2);
            __builtin_amdgcn_sched_barrier(0);   // pin the prefetch (no sink)
        }
    }

    // ---- epilogue (v7's verified mapping, 4-wave/32-row form)
    const int col   = w * 16 + m;
    const int batch = rb >> 11;
    const int seq0  = rb & (S - 1);
    #pragma unroll
    for (int h = 0; h < 2; ++h) {
        const int orow = rb + h * 16 + g * 4;
        #pragma unroll
        for (int r = 0; r < 4; ++r) {
            qo[(size_t)(orow + r) * Hd + col] = f2bf(accq[h][r] * 0.125f);
            ko[(size_t)(orow + r) * Hd + col] = f2bf(acck[h][r]);
        }
    }
    #pragma unroll
    for (int ns = 0; ns < 2; ++ns)
        #pragma unroll
        for (int r = 0; r < 4; ++r) {
            const int hc = w * 16 + g * 4 + r;
            vTo[(size_t)batch * Hd * S + (size_t)hc * S + seq0 + ns * 16 + m]
                = f2bf(accv[ns][r]);
        }
}

// ---------------------------------------------------------------------------
// Attention v10 (R1-measured version, untouched): LDS-staged K/V with
// coalesced uint4 loads, swapped-operand QK^T, lane-local PV via 16x16x16.
__global__ __launch_bounds__(256)
void attn_part(const ushort_t* __restrict__ q, const ushort_t* __restrict__ k,
               const ushort_t* __restrict__ vT,
               float* __restrict__ lp, ushort_t* __restrict__ op)
{
    const int bi     = blockIdx.x;
    const int parity = bi & 3;
    const int pr     = bi >> 2;
    const int batch  = pr & 7;
    const int tile   = 31 - (pr >> 3);   // longest-first
    const int qs0    = tile * 64;
    const int sidx   = (batch * 32 + tile) * 4 + parity;

    const ushort_t* kb  = k  + (size_t)batch * S * Hd;
    const ushort_t* vTb = vT + (size_t)batch * Hd * S;

    const int t    = threadIdx.x;
    const int w    = t >> 6;
    const int lane = t & 63;
    const int m    = lane & 15;
    const int g    = lane >> 4;

    __shared__ alignas(16) ushort_t KS [64][LSTA];
    __shared__ alignas(16) ushort_t VTS[64][LSTA];

    const ushort_t* qrow = q + (size_t)(batch * S + qs0 + w * 16 + m) * Hd;
    short8 qf0 = *(const short8*)(qrow + g * 8);
    short8 qf1 = *(const short8*)(qrow + 32 + g * 8);

    f32x4 o[4];
    #pragma unroll
    for (int j = 0; j < 4; ++j) o[j] = (f32x4){0.f, 0.f, 0.f, 0.f};
    float lrun = 0.f;
    const int qr = w * 16 + m;   // q row within the 64-row block (mask)

    const int r1 = t >> 3, c16 = (t & 7) * 8;
    uint4 pk0, pk1, pv0, pv1;

    int c = parity;
    if (c <= tile) {
        const int key0 = c * 64;
        const ushort_t* kt_base = kb + (size_t)key0 * Hd;   // 8 KB flat
        pk0 = *(const uint4*)(kt_base + t * 8);
        pk1 = *(const uint4*)(kt_base + (t + 256) * 8);
        pv0 = *(const uint4*)(vTb + (size_t)r1 * S + key0 + c16);
        pv1 = *(const uint4*)(vTb + (size_t)(r1 + 32) * S + key0 + c16);
    }

    for (; c <= tile; c += 4) {
        *(uint4*)&KS [r1][c16]       = pk0;
        *(uint4*)&KS [r1 + 32][c16]  = pk1;
        *(uint4*)&VTS[r1][c16]       = pv0;
        *(uint4*)&VTS[r1 + 32][c16]  = pv1;
        __syncthreads();

        if (c + 4 <= tile) {
            const int key0n = (c + 4) * 64;
            const ushort_t* kt_base = kb + (size_t)key0n * Hd;
            pk0 = *(const uint4*)(kt_base + t * 8);
            pk1 = *(const uint4*)(kt_base + (t + 256) * 8);
            pv0 = *(const uint4*)(vTb + (size_t)r1 * S + key0n + c16);
            pv1 = *(const uint4*)(vTb + (size_t)(r1 + 32) * S + key0n + c16);
        }

        // ---- S^T = K Q^T: sacc[nt][r] = S[q = w*16+m][key = nt*16+g*4+r]
        f32x4 sacc[4];
        #pragma unroll
        for (int j = 0; j < 4; ++j) sacc[j] = (f32x4){0.f, 0.f, 0.f, 0.f};
        #pragma unroll
        for (int nt = 0; nt < 4; ++nt) {
            short8 b0 = *(const short8*)&KS[nt * 16 + m][g * 8];
            short8 b1 = *(const short8*)&KS[nt * 16 + m][32 + g * 8];
            sacc[nt] = __builtin_amdgcn_mfma_f32_16x16x32_bf16(b0, qf0, sacc[nt], 0, 0, 0);
            sacc[nt] = __builtin_amdgcn_mfma_f32_16x16x32_bf16(b1, qf1, sacc[nt], 0, 0, 0);
        }

        // ---- P = exp(S), causal mask on the diagonal tile (no max shift)
        if (c == tile) {
            #pragma unroll
            for (int nt = 0; nt < 4; ++nt)
                #pragma unroll
                for (int r = 0; r < 4; ++r) {
                    const int keyl = nt * 16 + g * 4 + r;
                    sacc[nt][r] = (keyl > qr) ? 0.f : __expf(sacc[nt][r]);
                }
        } else {
            #pragma unroll
            for (int nt = 0; nt < 4; ++nt)
                #pragma unroll
                for (int r = 0; r < 4; ++r)
                    sacc[nt][r] = __expf(sacc[nt][r]);
        }

        // ---- per-lane l accumulation (q fixed = m per lane)
        #pragma unroll
        for (int nt = 0; nt < 4; ++nt)
            lrun += (sacc[nt][0] + sacc[nt][1]) + (sacc[nt][2] + sacc[nt][3]);

        // ---- pack P to bf16 (pairs -> v_cvt_pk_bf16_f32)
        unsigned pw0[4], pw1[4];
        #pragma unroll
        for (int s = 0; s < 4; ++s) {
            pw0[s] = packbf2(sacc[s][0], sacc[s][1]);
            pw1[s] = packbf2(sacc[s][2], sacc[s][3]);
        }

        // ---- O += P V via 16x16x16 (A-frag lane-local: no LDS, no shuffle)
        #pragma unroll
        for (int s = 0; s < 4; ++s) {
            short4v pa;
            { unsigned u2[2] = {pw0[s], pw1[s]}; __builtin_memcpy(&pa, u2, 8); }
            #pragma unroll
            for (int nt = 0; nt < 4; ++nt) {
                short4v vb = *(const short4v*)&VTS[nt * 16 + m][s * 16 + g * 4];
                o[nt] = __builtin_amdgcn_mfma_f32_16x16x16bf16_1k(pa, vb, o[nt], 0, 0, 0);
            }
        }
        __syncthreads();
    }

    // ---- final reduce of l across the 4 g-groups (q = m), write partial
    {
        float ts = lrun;
        ts += __shfl_xor(ts, 16, 64);
        ts += __shfl_xor(ts, 32, 64);
        if (lane < 16) lp[sidx * 64 + w * 16 + m] = ts;
    }
    #pragma unroll
    for (int nt = 0; nt < 4; ++nt)
        #pragma unroll
        for (int r = 0; r < 4; ++r)
            op[(size_t)sidx * 4096 + (w * 16 + g * 4 + r) * 64 + nt * 16 + m]
                = f2bf(o[nt][r]);
}

// ---------------------------------------------------------------------------
// Attention phase 2: plain sum-merge of 4 parity partials. Grid 256.
__global__ __launch_bounds__(256)
void attn_merge(const float* __restrict__ lp, const ushort_t* __restrict__ op,
                float* __restrict__ out)
{
    const int bq    = blockIdx.x;
    const int batch = bq >> 5;
    const int tile  = bq & 31;
    const int s0    = (batch * 32 + tile) * 4;

    const int t   = threadIdx.x;
    const int row = t >> 2;
    const int c16 = (t & 3) * 16;

    float l = 0.f;
    #pragma unroll
    for (int p = 0; p < 4; ++p) l += lp[(s0 + p) * 64 + row];
    const float inv = 1.f / l;

    float acc[16];
    #pragma unroll
    for (int j = 0; j < 16; ++j) acc[j] = 0.f;
    #pragma unroll
    for (int p = 0; p < 4; ++p) {
        short8 a0 = *(const short8*)(op + (size_t)(s0 + p) * 4096 + row * 64 + c16);
        short8 a1 = *(const short8*)(op + (size_t)(s0 + p) * 4096 + row * 64 + c16 + 8);
        #pragma unroll
        for (int j = 0; j < 8; ++j) {
            acc[j]     += bf2f((ushort_t)a0[j]);
            acc[j + 8] += bf2f((ushort_t)a1[j]);
        }
    }
    float* dst = out + (size_t)(batch * S + tile * 64 + row) * Hd + c16;
    #pragma unroll
    for (int j = 0; j < 16; ++j) dst[j] = acc[j] * inv;
}

// ---------------------------------------------------------------------------
extern "C" void kernel_launch(void* const* d_in, const int* in_sizes, int n_in,
                              void* d_out, int out_size, void* d_ws, size_t ws_size,
                              hipStream_t stream) {
    const float* x  = (const float*)d_in[0];
    const float* Wk = (const float*)d_in[1];
    const float* Wq = (const float*)d_in[2];
    const float* Wv = (const float*)d_in[3];
    float* out = (float*)d_out;

    ushort_t* qws  = (ushort_t*)d_ws;                      // 16384*64 bf16
    ushort_t* kws  = qws + (size_t)ROWS * Hd;
    ushort_t* vTws = kws + (size_t)ROWS * Hd;              // [8][64][2048] bf16
    ushort_t* WT   = vTws + (size_t)ROWS * Hd;             // 192*1024 bf16
    float*    lpp  = (float*)(WT + (size_t)NTOT * E);      // 1024*64 f32
    ushort_t* opp  = (ushort_t*)(lpp + 1024 * 64);         // 1024*4096 bf16

    prep_wt<<<(NTOT * E) / 256, 256, 0, stream>>>(Wk, Wq, Wv, WT);
    proj_v14<<<ROWS / BM, 256, 0, stream>>>(x, WT, qws, kws, vTws);
    attn_part<<<1024, 256, 0, stream>>>(qws, kws, vTws, lpp, opp);
    attn_merge<<<256, 256, 0, stream>>>(lpp, opp, out);
}

// Round 10
// 130.298 us; speedup vs baseline: 1.0519x; 1.0519x over previous
//
#include <hip/hip_runtime.h>
#include <hip/hip_bf16.h>

typedef unsigned short ushort_t;
typedef __attribute__((ext_vector_type(8))) short short8;   // 8 bf16 (4 VGPRs)
typedef __attribute__((ext_vector_type(4))) short short4v;  // 4 bf16 (2 VGPRs)
typedef __attribute__((ext_vector_type(4))) float f32x4;    // 4 fp32 acc

__device__ __forceinline__ float bf2f(ushort_t u) {
    unsigned int x = ((unsigned int)u) << 16;
    float f; __builtin_memcpy(&f, &x, 4); return f;
}
__device__ __forceinline__ ushort_t f2bf(float f) {
    __hip_bfloat16 h = __float2bfloat16(f);
    ushort_t u; __builtin_memcpy(&u, &h, 2); return u;
}
__device__ __forceinline__ unsigned packbf2(float a, float b) {
    return (unsigned)f2bf(a) | ((unsigned)f2bf(b) << 16);
}

// Direct-to-LDS DMA, 16B per lane. No dest VGPR -> the compiler cannot sink it.
__device__ __forceinline__ void gload16(const void* g, void* l) {
    __builtin_amdgcn_global_load_lds(
        (const __attribute__((address_space(1))) unsigned int*)g,
        (__attribute__((address_space(3))) unsigned int*)l, 16, 0, 0);
}

constexpr int E  = 1024;
constexpr int Hd = 64;
constexpr int S  = 2048;
constexpr int ROWS = 8 * 2048;   // 16384
constexpr int NTOT = 192;
constexpr int LSTA = 88;         // attn LDS row stride (R1-measured layout)
constexpr int BM   = 32;         // proj rows per block

// ---------------------------------------------------------------------------
// prep: WT[192][1024] bf16, rows 0-63 = Wq^T, 64-127 = Wk^T, 128-191 = Wv^T
__global__ __launch_bounds__(256)
void prep_wt(const float* __restrict__ Wk, const float* __restrict__ Wq,
             const float* __restrict__ Wv, ushort_t* __restrict__ WT)
{
    int idx = blockIdx.x * 256 + threadIdx.x;
    int n = idx >> 10;
    int kk = idx & 1023;
    const float* W = (n < 64) ? Wq : ((n < 128) ? Wk : Wv);
    int h = n & 63;
    WT[idx] = f2bf(W[kk * Hd + h]);
}

// ---------------------------------------------------------------------------
// Projection v15 = v13's counted-vmcnt DMA pipeline + TRUE 2 blocks/CU.
// v13's flaw: grid 256 = only 1 block available per CU, so every body's
// vmcnt-tail + barrier rendezvous was exposed with no co-resident chain to
// absorb it (m114). v15: BM=32 @ 512 threads -> grid 512, LDS 2x32KB = 64KB
// (2 blocks = 128KB <= 160), launch_bounds(512,4). All staging is
// global_load_lds (the only prefetch the compiler provably cannot sink:
// v7/v10/v14 reg-prefetch all died in regalloc, VGPR=52/56 proof).
// Ledger: 4 VMEM/thread/body (1 x-DMA + 3 w-DMA); prologue 8 outstanding;
// steady vmcnt(4) drains exactly body i; tail vmcnt(0). XOR swizzle as
// verified in v11/v12/v13 (key = row&7 = m&7 at every read site).
__global__ __launch_bounds__(512, 4)
void proj_v15(const float* __restrict__ x, const ushort_t* __restrict__ WT,
              ushort_t* __restrict__ qo, ushort_t* __restrict__ ko,
              ushort_t* __restrict__ vTo)
{
    __shared__ alignas(16) float    XS[2][BM * 64];    // 8KB x-tile  x2
    __shared__ alignas(16) ushort_t WS[2][192 * 64];   // 24KB w-tile x2

    const int t    = threadIdx.x;        // 0..511
    const int w    = t >> 6;             // 0..7
    const int lane = t & 63;
    const int m    = lane & 15;
    const int g    = lane >> 4;
    const int rl   = m & 7;              // swizzle key (row&7 == m&7 at reads)
    const int cg   = w & 3;              // col-group (16 of 64 cols)
    const int mh   = w >> 2;             // row-group (16 of 32 rows)
    const int rb   = blockIdx.x * BM;

    f32x4 accq = (f32x4){0.f, 0.f, 0.f, 0.f};
    f32x4 acck = (f32x4){0.f, 0.f, 0.f, 0.f};
    f32x4 accv = (f32x4){0.f, 0.f, 0.f, 0.f};

    // ---- staging sources (inverse-swizzled; unit = 16B)
    const int xr = t >> 4;                       // 0..31
    const int xu = (t & 15) ^ (xr & 7);
    const float* xsrc = x + (size_t)(rb + xr) * E + xu * 4;

    const ushort_t* wsrc[3];
    #pragma unroll
    for (int j = 0; j < 3; ++j) {
        const int L  = j * 512 + t;
        const int wr = L >> 3;                   // 0..191
        const int wu = (L & 7) ^ (wr & 7);
        wsrc[j] = WT + (size_t)wr * E + wu * 8;
    }

    // ---- fragment LDS offsets (lane constants)
    int xiA[2], xiB[2];                          // [kt], f32 index
    #pragma unroll
    for (int kt = 0; kt < 2; ++kt) {
        const int row = mh * 16 + m;
        const int U   = kt * 8 + 2 * g;
        xiA[kt] = (row * 16 + (U ^ rl)) * 4;
        xiB[kt] = (row * 16 + ((U + 1) ^ rl)) * 4;
    }
    int wiq[2], wik[2], wiv[2];                  // [kt], ushort index
    #pragma unroll
    for (int kt = 0; kt < 2; ++kt) {
        const int U = kt * 4 + g;
        wiq[kt] = ((      cg * 16 + m) * 8 + (U ^ rl)) * 8;
        wik[kt] = ((64  + cg * 16 + m) * 8 + (U ^ rl)) * 8;
        wiv[kt] = ((128 + cg * 16 + m) * 8 + (U ^ rl)) * 8;
    }

    auto STAGE = [&](int buf, int c) {           // 4 gload16 / thread
        const int k0 = c * 64;
        char* xb = (char*)&XS[buf][0];
        char* wb = (char*)&WS[buf][0];
        gload16(xsrc + k0, xb + (size_t)t * 16);
        #pragma unroll
        for (int j = 0; j < 3; ++j)
            gload16(wsrc[j] + k0, wb + (size_t)(j * 512 + t) * 16);
    };

    auto COMPUTE = [&](int buf) {
        #pragma unroll
        for (int kt = 0; kt < 2; ++kt) {
            short8 fq = *(const short8*)&WS[buf][wiq[kt]];
            short8 fk = *(const short8*)&WS[buf][wik[kt]];
            short8 fv = *(const short8*)&WS[buf][wiv[kt]];
            float4 A = *(const float4*)&XS[buf][xiA[kt]];
            float4 B = *(const float4*)&XS[buf][xiB[kt]];
            short8 a;
            {
                unsigned u4[4];
                u4[0] = packbf2(A.x, A.y);
                u4[1] = packbf2(A.z, A.w);
                u4[2] = packbf2(B.x, B.y);
                u4[3] = packbf2(B.z, B.w);
                __builtin_memcpy(&a, u4, 16);
            }
            accq = __builtin_amdgcn_mfma_f32_16x16x32_bf16(a, fq, accq, 0, 0, 0);
            acck = __builtin_amdgcn_mfma_f32_16x16x32_bf16(a, fk, acck, 0, 0, 0);
            accv = __builtin_amdgcn_mfma_f32_16x16x32_bf16(fv, a, accv, 0, 0, 0);
        }
    };

    // ---- prologue: bodies 0,1 in flight (8 VMEM outstanding / thread)
    STAGE(0, 0);
    STAGE(1, 1);

    // ---- main loop. At iter i's wait: outstanding = body i (4) + body i+1
    // (4); vmcnt(4) drains exactly body i. STAGE(i+2) reuses buf[i%2] only
    // after barrier2 (all waves finished reading it in COMPUTE).
    #pragma unroll
    for (int i = 0; i < 16; ++i) {
        if (i < 15) { asm volatile("s_waitcnt vmcnt(4)" ::: "memory"); }
        else        { asm volatile("s_waitcnt vmcnt(0)" ::: "memory"); }
        __builtin_amdgcn_sched_barrier(0);
        __builtin_amdgcn_s_barrier();
        COMPUTE(i & 1);
        __builtin_amdgcn_s_barrier();
        if (i + 2 < 16) STAGE(i & 1, i + 2);
    }

    // ---- epilogue (v13 mapping with the h-dimension removed)
    const int col   = cg * 16 + m;
    const int batch = rb >> 11;
    const int seq0  = rb & (S - 1);
    const int orow  = rb + mh * 16 + g * 4;
    #pragma unroll
    for (int r = 0; r < 4; ++r) {
        qo[(size_t)(orow + r) * Hd + col] = f2bf(accq[r] * 0.125f);
        ko[(size_t)(orow + r) * Hd + col] = f2bf(acck[r]);
    }
    #pragma unroll
    for (int r = 0; r < 4; ++r) {
        const int hc = cg * 16 + g * 4 + r;
        vTo[(size_t)batch * Hd * S + (size_t)hc * S + seq0 + mh * 16 + m]
            = f2bf(accv[r]);
    }
}

// ---------------------------------------------------------------------------
// Attention v10 (R1-measured version, untouched): LDS-staged K/V with
// coalesced uint4 loads, swapped-operand QK^T, lane-local PV via 16x16x16.
__global__ __launch_bounds__(256)
void attn_part(const ushort_t* __restrict__ q, const ushort_t* __restrict__ k,
               const ushort_t* __restrict__ vT,
               float* __restrict__ lp, ushort_t* __restrict__ op)
{
    const int bi     = blockIdx.x;
    const int parity = bi & 3;
    const int pr     = bi >> 2;
    const int batch  = pr & 7;
    const int tile   = 31 - (pr >> 3);   // longest-first
    const int qs0    = tile * 64;
    const int sidx   = (batch * 32 + tile) * 4 + parity;

    const ushort_t* kb  = k  + (size_t)batch * S * Hd;
    const ushort_t* vTb = vT + (size_t)batch * Hd * S;

    const int t    = threadIdx.x;
    const int w    = t >> 6;
    const int lane = t & 63;
    const int m    = lane & 15;
    const int g    = lane >> 4;

    __shared__ alignas(16) ushort_t KS [64][LSTA];
    __shared__ alignas(16) ushort_t VTS[64][LSTA];

    const ushort_t* qrow = q + (size_t)(batch * S + qs0 + w * 16 + m) * Hd;
    short8 qf0 = *(const short8*)(qrow + g * 8);
    short8 qf1 = *(const short8*)(qrow + 32 + g * 8);

    f32x4 o[4];
    #pragma unroll
    for (int j = 0; j < 4; ++j) o[j] = (f32x4){0.f, 0.f, 0.f, 0.f};
    float lrun = 0.f;
    const int qr = w * 16 + m;   // q row within the 64-row block (mask)

    const int r1 = t >> 3, c16 = (t & 7) * 8;
    uint4 pk0, pk1, pv0, pv1;

    int c = parity;
    if (c <= tile) {
        const int key0 = c * 64;
        const ushort_t* kt_base = kb + (size_t)key0 * Hd;   // 8 KB flat
        pk0 = *(const uint4*)(kt_base + t * 8);
        pk1 = *(const uint4*)(kt_base + (t + 256) * 8);
        pv0 = *(const uint4*)(vTb + (size_t)r1 * S + key0 + c16);
        pv1 = *(const uint4*)(vTb + (size_t)(r1 + 32) * S + key0 + c16);
    }

    for (; c <= tile; c += 4) {
        *(uint4*)&KS [r1][c16]       = pk0;
        *(uint4*)&KS [r1 + 32][c16]  = pk1;
        *(uint4*)&VTS[r1][c16]       = pv0;
        *(uint4*)&VTS[r1 + 32][c16]  = pv1;
        __syncthreads();

        if (c + 4 <= tile) {
            const int key0n = (c + 4) * 64;
            const ushort_t* kt_base = kb + (size_t)key0n * Hd;
            pk0 = *(const uint4*)(kt_base + t * 8);
            pk1 = *(const uint4*)(kt_base + (t + 256) * 8);
            pv0 = *(const uint4*)(vTb + (size_t)r1 * S + key0n + c16);
            pv1 = *(const uint4*)(vTb + (size_t)(r1 + 32) * S + key0n + c16);
        }

        // ---- S^T = K Q^T: sacc[nt][r] = S[q = w*16+m][key = nt*16+g*4+r]
        f32x4 sacc[4];
        #pragma unroll
        for (int j = 0; j < 4; ++j) sacc[j] = (f32x4){0.f, 0.f, 0.f, 0.f};
        #pragma unroll
        for (int nt = 0; nt < 4; ++nt) {
            short8 b0 = *(const short8*)&KS[nt * 16 + m][g * 8];
            short8 b1 = *(const short8*)&KS[nt * 16 + m][32 + g * 8];
            sacc[nt] = __builtin_amdgcn_mfma_f32_16x16x32_bf16(b0, qf0, sacc[nt], 0, 0, 0);
            sacc[nt] = __builtin_amdgcn_mfma_f32_16x16x32_bf16(b1, qf1, sacc[nt], 0, 0, 0);
        }

        // ---- P = exp(S), causal mask on the diagonal tile (no max shift)
        if (c == tile) {
            #pragma unroll
            for (int nt = 0; nt < 4; ++nt)
                #pragma unroll
                for (int r = 0; r < 4; ++r) {
                    const int keyl = nt * 16 + g * 4 + r;
                    sacc[nt][r] = (keyl > qr) ? 0.f : __expf(sacc[nt][r]);
                }
        } else {
            #pragma unroll
            for (int nt = 0; nt < 4; ++nt)
                #pragma unroll
                for (int r = 0; r < 4; ++r)
                    sacc[nt][r] = __expf(sacc[nt][r]);
        }

        // ---- per-lane l accumulation (q fixed = m per lane)
        #pragma unroll
        for (int nt = 0; nt < 4; ++nt)
            lrun += (sacc[nt][0] + sacc[nt][1]) + (sacc[nt][2] + sacc[nt][3]);

        // ---- pack P to bf16 (pairs -> v_cvt_pk_bf16_f32)
        unsigned pw0[4], pw1[4];
        #pragma unroll
        for (int s = 0; s < 4; ++s) {
            pw0[s] = packbf2(sacc[s][0], sacc[s][1]);
            pw1[s] = packbf2(sacc[s][2], sacc[s][3]);
        }

        // ---- O += P V via 16x16x16 (A-frag lane-local: no LDS, no shuffle)
        #pragma unroll
        for (int s = 0; s < 4; ++s) {
            short4v pa;
            { unsigned u2[2] = {pw0[s], pw1[s]}; __builtin_memcpy(&pa, u2, 8); }
            #pragma unroll
            for (int nt = 0; nt < 4; ++nt) {
                short4v vb = *(const short4v*)&VTS[nt * 16 + m][s * 16 + g * 4];
                o[nt] = __builtin_amdgcn_mfma_f32_16x16x16bf16_1k(pa, vb, o[nt], 0, 0, 0);
            }
        }
        __syncthreads();
    }

    // ---- final reduce of l across the 4 g-groups (q = m), write partial
    {
        float ts = lrun;
        ts += __shfl_xor(ts, 16, 64);
        ts += __shfl_xor(ts, 32, 64);
        if (lane < 16) lp[sidx * 64 + w * 16 + m] = ts;
    }
    #pragma unroll
    for (int nt = 0; nt < 4; ++nt)
        #pragma unroll
        for (int r = 0; r < 4; ++r)
            op[(size_t)sidx * 4096 + (w * 16 + g * 4 + r) * 64 + nt * 16 + m]
                = f2bf(o[nt][r]);
}

// ---------------------------------------------------------------------------
// Attention phase 2: plain sum-merge of 4 parity partials. Grid 256.
__global__ __launch_bounds__(256)
void attn_merge(const float* __restrict__ lp, const ushort_t* __restrict__ op,
                float* __restrict__ out)
{
    const int bq    = blockIdx.x;
    const int batch = bq >> 5;
    const int tile  = bq & 31;
    const int s0    = (batch * 32 + tile) * 4;

    const int t   = threadIdx.x;
    const int row = t >> 2;
    const int c16 = (t & 3) * 16;

    float l = 0.f;
    #pragma unroll
    for (int p = 0; p < 4; ++p) l += lp[(s0 + p) * 64 + row];
    const float inv = 1.f / l;

    float acc[16];
    #pragma unroll
    for (int j = 0; j < 16; ++j) acc[j] = 0.f;
    #pragma unroll
    for (int p = 0; p < 4; ++p) {
        short8 a0 = *(const short8*)(op + (size_t)(s0 + p) * 4096 + row * 64 + c16);
        short8 a1 = *(const short8*)(op + (size_t)(s0 + p) * 4096 + row * 64 + c16 + 8);
        #pragma unroll
        for (int j = 0; j < 8; ++j) {
            acc[j]     += bf2f((ushort_t)a0[j]);
            acc[j + 8] += bf2f((ushort_t)a1[j]);
        }
    }
    float* dst = out + (size_t)(batch * S + tile * 64 + row) * Hd + c16;
    #pragma unroll
    for (int j = 0; j < 16; ++j) dst[j] = acc[j] * inv;
}

// ---------------------------------------------------------------------------
extern "C" void kernel_launch(void* const* d_in, const int* in_sizes, int n_in,
                              void* d_out, int out_size, void* d_ws, size_t ws_size,
                              hipStream_t stream) {
    const float* x  = (const float*)d_in[0];
    const float* Wk = (const float*)d_in[1];
    const float* Wq = (const float*)d_in[2];
    const float* Wv = (const float*)d_in[3];
    float* out = (float*)d_out;

    ushort_t* qws  = (ushort_t*)d_ws;                      // 16384*64 bf16
    ushort_t* kws  = qws + (size_t)ROWS * Hd;
    ushort_t* vTws = kws + (size_t)ROWS * Hd;              // [8][64][2048] bf16
    ushort_t* WT   = vTws + (size_t)ROWS * Hd;             // 192*1024 bf16
    float*    lpp  = (float*)(WT + (size_t)NTOT * E);      // 1024*64 f32
    ushort_t* opp  = (ushort_t*)(lpp + 1024 * 64);         // 1024*4096 bf16

    prep_wt<<<(NTOT * E) / 256, 256, 0, stream>>>(Wk, Wq, Wv, WT);
    proj_v15<<<ROWS / BM, 512, 0, stream>>>(x, WT, qws, kws, vTws);
    attn_part<<<1024, 256, 0, stream>>>(qws, kws, vTws, lpp, opp);
    attn_merge<<<256, 256, 0, stream>>>(lpp, opp, out);
}

// Round 11
// 127.541 us; speedup vs baseline: 1.0747x; 1.0216x over previous
//
#include <hip/hip_runtime.h>
#include <hip/hip_bf16.h>

typedef unsigned short ushort_t;
typedef __attribute__((ext_vector_type(8))) short short8;   // 8 bf16 (4 VGPRs)
typedef __attribute__((ext_vector_type(4))) short short4v;  // 4 bf16 (2 VGPRs)
typedef __attribute__((ext_vector_type(4))) float f32x4;    // 4 fp32 acc

__device__ __forceinline__ float bf2f(ushort_t u) {
    unsigned int x = ((unsigned int)u) << 16;
    float f; __builtin_memcpy(&f, &x, 4); return f;
}
__device__ __forceinline__ ushort_t f2bf(float f) {
    __hip_bfloat16 h = __float2bfloat16(f);
    ushort_t u; __builtin_memcpy(&u, &h, 2); return u;
}
__device__ __forceinline__ unsigned packbf2(float a, float b) {
    return (unsigned)f2bf(a) | ((unsigned)f2bf(b) << 16);
}

// Direct-to-LDS DMA, 16B per lane. No dest VGPR -> the compiler cannot sink it.
__device__ __forceinline__ void gload16(const void* g, void* l) {
    __builtin_amdgcn_global_load_lds(
        (const __attribute__((address_space(1))) unsigned int*)g,
        (__attribute__((address_space(3))) unsigned int*)l, 16, 0, 0);
}

constexpr int E  = 1024;
constexpr int Hd = 64;
constexpr int S  = 2048;
constexpr int ROWS = 8 * 2048;   // 16384
constexpr int NTOT = 192;
constexpr int LSTA = 88;         // attn LDS row stride (R1-measured layout)
constexpr int BM   = 64;         // proj rows per block

// ---------------------------------------------------------------------------
// prep: WT[192][1024] bf16, rows 0-63 = Wq^T, 64-127 = Wk^T, 128-191 = Wv^T
__global__ __launch_bounds__(256)
void prep_wt(const float* __restrict__ Wk, const float* __restrict__ Wq,
             const float* __restrict__ Wv, ushort_t* __restrict__ WT)
{
    int idx = blockIdx.x * 256 + threadIdx.x;
    int n = idx >> 10;
    int kk = idx & 1023;
    const float* W = (n < 64) ? Wq : ((n < 128) ? Wk : Wv);
    int h = n & 63;
    WT[idx] = f2bf(W[kk * Hd + h]);
}

// ---------------------------------------------------------------------------
// Projection v13 (session-best, measured 129.0/129.5 total in R7/R8):
// BM=64, 512 threads, 2-buffer counted-vmcnt DMA pipeline. All staging via
// global_load_lds (the only prefetch the compiler cannot sink; reg-prefetch
// died in regalloc in v7/v10/v14, VGPR=52/56 proofs). Steady-state
// `s_waitcnt vmcnt(5)` drains exactly body i while body i+1 stays in
// flight; STAGE(i+2) issues after barrier2. XOR swizzle verified in
// v11/v12/v13 (key = row&7 = m&7 at every read site).
// Structural plateau (R7-R10): bytes x parallelism is machine-forced --
// weight restaging = (ROWS/BM)*384KB; BM=64@grid256 (164MB, 5.2TB/s
// delivered) == BM=32@grid512 2-chain (262MB, 8TB/s) == ~31us.
__global__ __launch_bounds__(512, 4)
void proj_v13(const float* __restrict__ x, const ushort_t* __restrict__ WT,
              ushort_t* __restrict__ qo, ushort_t* __restrict__ ko,
              ushort_t* __restrict__ vTo)
{
    __shared__ alignas(16) float    XS[2][BM * 64];    // 16KB x-tile   x2
    __shared__ alignas(16) ushort_t WS[2][192 * 64];   // 24KB w-tile   x2

    const int t    = threadIdx.x;        // 0..511
    const int w    = t >> 6;             // 0..7
    const int lane = t & 63;
    const int m    = lane & 15;
    const int g    = lane >> 4;
    const int rl   = m & 7;              // swizzle key (row&7 == m&7 at all reads)
    const int cg   = w & 3;              // col-group (16 cols of 64)
    const int mh   = w >> 2;             // row-half  (32 rows of 64)
    const int rb   = blockIdx.x * BM;

    f32x4 accq[2], acck[2], accv[2];
    #pragma unroll
    for (int j = 0; j < 2; ++j) {
        accq[j] = (f32x4){0.f, 0.f, 0.f, 0.f};
        acck[j] = (f32x4){0.f, 0.f, 0.f, 0.f};
        accv[j] = (f32x4){0.f, 0.f, 0.f, 0.f};
    }

    // ---- staging sources (inverse-swizzled; unit = 16B)
    const int xr0 = t >> 4,         xu0 = (t & 15) ^ (xr0 & 7);
    const int xr1 = (t + 512) >> 4, xu1 = (t & 15) ^ (xr1 & 7);
    const float* xsrc0 = x + (size_t)(rb + xr0) * E + xu0 * 4;
    const float* xsrc1 = x + (size_t)(rb + xr1) * E + xu1 * 4;

    const ushort_t* wsrc[3];
    #pragma unroll
    for (int j = 0; j < 3; ++j) {
        const int L  = j * 512 + t;
        const int wr = L >> 3;
        const int wu = (L & 7) ^ (wr & 7);
        wsrc[j] = WT + (size_t)wr * E + wu * 8;
    }

    // ---- fragment LDS offsets (lane constants)
    int xiA[2][2], xiB[2][2];                 // [h][kt], f32 index
    #pragma unroll
    for (int h = 0; h < 2; ++h)
        #pragma unroll
        for (int kt = 0; kt < 2; ++kt) {
            const int row = mh * 32 + h * 16 + m;
            const int U   = kt * 8 + 2 * g;
            xiA[h][kt] = (row * 16 + (U ^ rl)) * 4;
            xiB[h][kt] = (row * 16 + ((U + 1) ^ rl)) * 4;
        }
    int wiq[2], wik[2], wiv[2];               // [kt], ushort index
    #pragma unroll
    for (int kt = 0; kt < 2; ++kt) {
        const int U = kt * 4 + g;
        wiq[kt] = ((      cg * 16 + m) * 8 + (U ^ rl)) * 8;
        wik[kt] = ((64  + cg * 16 + m) * 8 + (U ^ rl)) * 8;
        wiv[kt] = ((128 + cg * 16 + m) * 8 + (U ^ rl)) * 8;
    }

    auto STAGE = [&](int buf, int c) {        // 5 gload16 / thread
        const int k0 = c * 64;
        char* xb = (char*)&XS[buf][0];
        char* wb = (char*)&WS[buf][0];
        gload16(xsrc0 + k0, xb + (size_t)t * 16);
        gload16(xsrc1 + k0, xb + (size_t)(t + 512) * 16);
        #pragma unroll
        for (int j = 0; j < 3; ++j)
            gload16(wsrc[j] + k0, wb + (size_t)(j * 512 + t) * 16);
    };

    auto COMPUTE = [&](int buf) {
        #pragma unroll
        for (int kt = 0; kt < 2; ++kt) {
            short8 fq = *(const short8*)&WS[buf][wiq[kt]];
            short8 fk = *(const short8*)&WS[buf][wik[kt]];
            short8 fv = *(const short8*)&WS[buf][wiv[kt]];
            #pragma unroll
            for (int h = 0; h < 2; ++h) {
                float4 A = *(const float4*)&XS[buf][xiA[h][kt]];
                float4 B = *(const float4*)&XS[buf][xiB[h][kt]];
                short8 a;
                {
                    unsigned u4[4];
                    u4[0] = packbf2(A.x, A.y);
                    u4[1] = packbf2(A.z, A.w);
                    u4[2] = packbf2(B.x, B.y);
                    u4[3] = packbf2(B.z, B.w);
                    __builtin_memcpy(&a, u4, 16);
                }
                accq[h] = __builtin_amdgcn_mfma_f32_16x16x32_bf16(a, fq, accq[h], 0, 0, 0);
                acck[h] = __builtin_amdgcn_mfma_f32_16x16x32_bf16(a, fk, acck[h], 0, 0, 0);
                accv[h] = __builtin_amdgcn_mfma_f32_16x16x32_bf16(fv, a, accv[h], 0, 0, 0);
            }
        }
    };

    // ---- prologue: 2 bodies in flight (10 loads/thread outstanding)
    STAGE(0, 0);
    STAGE(1, 1);

    // ---- main loop. Ledger: at iter i's wait, outstanding = body i (5) +
    // body i+1 (5) = 10; vmcnt(5) drains exactly body i. STAGE(i+2) reuses
    // buf[i%2] only after barrier2 (all waves done reading it in COMPUTE).
    #pragma unroll
    for (int i = 0; i < 16; ++i) {
        if (i < 15) { asm volatile("s_waitcnt vmcnt(5)" ::: "memory"); }
        else        { asm volatile("s_waitcnt vmcnt(0)" ::: "memory"); }
        __builtin_amdgcn_sched_barrier(0);
        __builtin_amdgcn_s_barrier();
        COMPUTE(i & 1);
        __builtin_amdgcn_s_barrier();
        if (i + 2 < 16) STAGE(i & 1, i + 2);
    }

    // ---- epilogue
    const int col   = cg * 16 + m;
    const int batch = rb >> 11;
    const int seq0  = rb & (S - 1);
    #pragma unroll
    for (int h = 0; h < 2; ++h) {
        const int orow = rb + mh * 32 + h * 16 + g * 4;
        #pragma unroll
        for (int r = 0; r < 4; ++r) {
            qo[(size_t)(orow + r) * Hd + col] = f2bf(accq[h][r] * 0.125f);
            ko[(size_t)(orow + r) * Hd + col] = f2bf(acck[h][r]);
        }
    }
    #pragma unroll
    for (int ns = 0; ns < 2; ++ns)
        #pragma unroll
        for (int r = 0; r < 4; ++r) {
            const int hc = cg * 16 + g * 4 + r;
            vTo[(size_t)batch * Hd * S + (size_t)hc * S + seq0 + mh * 32 + ns * 16 + m]
                = f2bf(accv[ns][r]);
        }
}

// ---------------------------------------------------------------------------
// Attention v10 (R1-measured version, untouched): LDS-staged K/V with
// coalesced uint4 loads, swapped-operand QK^T, lane-local PV via 16x16x16.
__global__ __launch_bounds__(256)
void attn_part(const ushort_t* __restrict__ q, const ushort_t* __restrict__ k,
               const ushort_t* __restrict__ vT,
               float* __restrict__ lp, ushort_t* __restrict__ op)
{
    const int bi     = blockIdx.x;
    const int parity = bi & 3;
    const int pr     = bi >> 2;
    const int batch  = pr & 7;
    const int tile   = 31 - (pr >> 3);   // longest-first
    const int qs0    = tile * 64;
    const int sidx   = (batch * 32 + tile) * 4 + parity;

    const ushort_t* kb  = k  + (size_t)batch * S * Hd;
    const ushort_t* vTb = vT + (size_t)batch * Hd * S;

    const int t    = threadIdx.x;
    const int w    = t >> 6;
    const int lane = t & 63;
    const int m    = lane & 15;
    const int g    = lane >> 4;

    __shared__ alignas(16) ushort_t KS [64][LSTA];
    __shared__ alignas(16) ushort_t VTS[64][LSTA];

    const ushort_t* qrow = q + (size_t)(batch * S + qs0 + w * 16 + m) * Hd;
    short8 qf0 = *(const short8*)(qrow + g * 8);
    short8 qf1 = *(const short8*)(qrow + 32 + g * 8);

    f32x4 o[4];
    #pragma unroll
    for (int j = 0; j < 4; ++j) o[j] = (f32x4){0.f, 0.f, 0.f, 0.f};
    float lrun = 0.f;
    const int qr = w * 16 + m;   // q row within the 64-row block (mask)

    const int r1 = t >> 3, c16 = (t & 7) * 8;
    uint4 pk0, pk1, pv0, pv1;

    int c = parity;
    if (c <= tile) {
        const int key0 = c * 64;
        const ushort_t* kt_base = kb + (size_t)key0 * Hd;   // 8 KB flat
        pk0 = *(const uint4*)(kt_base + t * 8);
        pk1 = *(const uint4*)(kt_base + (t + 256) * 8);
        pv0 = *(const uint4*)(vTb + (size_t)r1 * S + key0 + c16);
        pv1 = *(const uint4*)(vTb + (size_t)(r1 + 32) * S + key0 + c16);
    }

    for (; c <= tile; c += 4) {
        *(uint4*)&KS [r1][c16]       = pk0;
        *(uint4*)&KS [r1 + 32][c16]  = pk1;
        *(uint4*)&VTS[r1][c16]       = pv0;
        *(uint4*)&VTS[r1 + 32][c16]  = pv1;
        __syncthreads();

        if (c + 4 <= tile) {
            const int key0n = (c + 4) * 64;
            const ushort_t* kt_base = kb + (size_t)key0n * Hd;
            pk0 = *(const uint4*)(kt_base + t * 8);
            pk1 = *(const uint4*)(kt_base + (t + 256) * 8);
            pv0 = *(const uint4*)(vTb + (size_t)r1 * S + key0n + c16);
            pv1 = *(const uint4*)(vTb + (size_t)(r1 + 32) * S + key0n + c16);
        }

        // ---- S^T = K Q^T: sacc[nt][r] = S[q = w*16+m][key = nt*16+g*4+r]
        f32x4 sacc[4];
        #pragma unroll
        for (int j = 0; j < 4; ++j) sacc[j] = (f32x4){0.f, 0.f, 0.f, 0.f};
        #pragma unroll
        for (int nt = 0; nt < 4; ++nt) {
            short8 b0 = *(const short8*)&KS[nt * 16 + m][g * 8];
            short8 b1 = *(const short8*)&KS[nt * 16 + m][32 + g * 8];
            sacc[nt] = __builtin_amdgcn_mfma_f32_16x16x32_bf16(b0, qf0, sacc[nt], 0, 0, 0);
            sacc[nt] = __builtin_amdgcn_mfma_f32_16x16x32_bf16(b1, qf1, sacc[nt], 0, 0, 0);
        }

        // ---- P = exp(S), causal mask on the diagonal tile (no max shift)
        if (c == tile) {
            #pragma unroll
            for (int nt = 0; nt < 4; ++nt)
                #pragma unroll
                for (int r = 0; r < 4; ++r) {
                    const int keyl = nt * 16 + g * 4 + r;
                    sacc[nt][r] = (keyl > qr) ? 0.f : __expf(sacc[nt][r]);
                }
        } else {
            #pragma unroll
            for (int nt = 0; nt < 4; ++nt)
                #pragma unroll
                for (int r = 0; r < 4; ++r)
                    sacc[nt][r] = __expf(sacc[nt][r]);
        }

        // ---- per-lane l accumulation (q fixed = m per lane)
        #pragma unroll
        for (int nt = 0; nt < 4; ++nt)
            lrun += (sacc[nt][0] + sacc[nt][1]) + (sacc[nt][2] + sacc[nt][3]);

        // ---- pack P to bf16 (pairs -> v_cvt_pk_bf16_f32)
        unsigned pw0[4], pw1[4];
        #pragma unroll
        for (int s = 0; s < 4; ++s) {
            pw0[s] = packbf2(sacc[s][0], sacc[s][1]);
            pw1[s] = packbf2(sacc[s][2], sacc[s][3]);
        }

        // ---- O += P V via 16x16x16 (A-frag lane-local: no LDS, no shuffle)
        #pragma unroll
        for (int s = 0; s < 4; ++s) {
            short4v pa;
            { unsigned u2[2] = {pw0[s], pw1[s]}; __builtin_memcpy(&pa, u2, 8); }
            #pragma unroll
            for (int nt = 0; nt < 4; ++nt) {
                short4v vb = *(const short4v*)&VTS[nt * 16 + m][s * 16 + g * 4];
                o[nt] = __builtin_amdgcn_mfma_f32_16x16x16bf16_1k(pa, vb, o[nt], 0, 0, 0);
            }
        }
        __syncthreads();
    }

    // ---- final reduce of l across the 4 g-groups (q = m), write partial
    {
        float ts = lrun;
        ts += __shfl_xor(ts, 16, 64);
        ts += __shfl_xor(ts, 32, 64);
        if (lane < 16) lp[sidx * 64 + w * 16 + m] = ts;
    }
    #pragma unroll
    for (int nt = 0; nt < 4; ++nt)
        #pragma unroll
        for (int r = 0; r < 4; ++r)
            op[(size_t)sidx * 4096 + (w * 16 + g * 4 + r) * 64 + nt * 16 + m]
                = f2bf(o[nt][r]);
}

// ---------------------------------------------------------------------------
// Attention phase 2: plain sum-merge of 4 parity partials. Grid 256.
__global__ __launch_bounds__(256)
void attn_merge(const float* __restrict__ lp, const ushort_t* __restrict__ op,
                float* __restrict__ out)
{
    const int bq    = blockIdx.x;
    const int batch = bq >> 5;
    const int tile  = bq & 31;
    const int s0    = (batch * 32 + tile) * 4;

    const int t   = threadIdx.x;
    const int row = t >> 2;
    const int c16 = (t & 3) * 16;

    float l = 0.f;
    #pragma unroll
    for (int p = 0; p < 4; ++p) l += lp[(s0 + p) * 64 + row];
    const float inv = 1.f / l;

    float acc[16];
    #pragma unroll
    for (int j = 0; j < 16; ++j) acc[j] = 0.f;
    #pragma unroll
    for (int p = 0; p < 4; ++p) {
        short8 a0 = *(const short8*)(op + (size_t)(s0 + p) * 4096 + row * 64 + c16);
        short8 a1 = *(const short8*)(op + (size_t)(s0 + p) * 4096 + row * 64 + c16 + 8);
        #pragma unroll
        for (int j = 0; j < 8; ++j) {
            acc[j]     += bf2f((ushort_t)a0[j]);
            acc[j + 8] += bf2f((ushort_t)a1[j]);
        }
    }
    float* dst = out + (size_t)(batch * S + tile * 64 + row) * Hd + c16;
    #pragma unroll
    for (int j = 0; j < 16; ++j) dst[j] = acc[j] * inv;
}

// ---------------------------------------------------------------------------
extern "C" void kernel_launch(void* const* d_in, const int* in_sizes, int n_in,
                              void* d_out, int out_size, void* d_ws, size_t ws_size,
                              hipStream_t stream) {
    const float* x  = (const float*)d_in[0];
    const float* Wk = (const float*)d_in[1];
    const float* Wq = (const float*)d_in[2];
    const float* Wv = (const float*)d_in[3];
    float* out = (float*)d_out;

    ushort_t* qws  = (ushort_t*)d_ws;                      // 16384*64 bf16
    ushort_t* kws  = qws + (size_t)ROWS * Hd;
    ushort_t* vTws = kws + (size_t)ROWS * Hd;              // [8][64][2048] bf16
    ushort_t* WT   = vTws + (size_t)ROWS * Hd;             // 192*1024 bf16
    float*    lpp  = (float*)(WT + (size_t)NTOT * E);      // 1024*64 f32
    ushort_t* opp  = (ushort_t*)(lpp + 1024 * 64);         // 1024*4096 bf16

    prep_wt<<<(NTOT * E) / 256, 256, 0, stream>>>(Wk, Wq, Wv, WT);
    proj_v13<<<ROWS / BM, 512, 0, stream>>>(x, WT, qws, kws, vTws);
    attn_part<<<1024, 256, 0, stream>>>(qws, kws, vTws, lpp, opp);
    attn_merge<<<256, 256, 0, stream>>>(lpp, opp, out);
}